// Round 13
// baseline (329.770 us; speedup 1.0000x reference)
//
#include <hip/hip_runtime.h>
#include <hip/hip_fp16.h>

// DCell forward, MI355X (gfx950). All inputs/outputs fp32.
// R13: pack kernel rebuilt with WIDE reads — 16 B/lane dense float4 pairs
// (1 KB/wave-instr, fill-kernel width) instead of 4 B/lane (256 B/instr).
// Block covers 256 consecutive (b,t) rows = 64 KB contiguous; each thread
// contributes one predicate byte to an LDS u64 row, one barrier, one 8-B
// store. Tests whether pack was transaction-limited (~68us) or HBM-bound
// (~30us, then neutral). Downstream identical to R12 (passed):
// MFMA 16x16x32 f16 per term, u64 gene bitmask A-frags (exact bit trick),
// block-local BN (bias cancels), LDS-transposed dense epilogues, h* fp16.
// ws: [gTb3 u64 | gTb2 | gTb1 | h3 fp16 | h2 fp16 | h1 fp16 | z0p] ~33 MB.

#define DEV static __device__ __forceinline__

constexpr int B_  = 256, G_ = 64, D_ = 20;
constexpr int T3_ = 2048, T2_ = 512, T1_ = 128;
constexpr float EPS_ = 1e-5f;

typedef unsigned char u8;
typedef unsigned long long u64;

constexpr size_t OFF_GTB3 = 0;
constexpr size_t SZ_GTB3 = (size_t)T3_ * B_ * 8;
constexpr size_t OFF_GTB2 = OFF_GTB3 + SZ_GTB3;
constexpr size_t SZ_GTB2 = (size_t)T2_ * B_ * 8;
constexpr size_t OFF_GTB1 = OFF_GTB2 + SZ_GTB2;
constexpr size_t SZ_GTB1 = (size_t)T1_ * B_ * 8;
constexpr size_t OFF_H3B = OFF_GTB1 + SZ_GTB1;
constexpr size_t SZ_H3 = (size_t)T3_ * B_ * D_ * 2;
constexpr size_t OFF_H2B = OFF_H3B + SZ_H3;
constexpr size_t SZ_H2 = (size_t)T2_ * B_ * D_ * 2;
constexpr size_t OFF_H1B = OFF_H2B + SZ_H2;
constexpr size_t SZ_H1 = (size_t)T1_ * B_ * D_ * 2;
constexpr size_t OFF_Z0B = OFF_H1B + SZ_H1;

typedef _Float16 half8_t __attribute__((ext_vector_type(8)));
typedef float f32x4 __attribute__((ext_vector_type(4)));

DEV half8_t as_h8(uint4 u) {
    union { uint4 u4; half8_t h; } c; c.u4 = u; return c.h;
}

// 8 gene BITS -> half8 {0.0h,1.0h}. Exact (no carries: operands are 0/1).
DEV half8_t bits8_to_h8(uint byte) {
    uint4 r;
    r.x = ((byte & 1u)        | ((byte & 2u)   << 15)) * 0x3C00u;
    r.y = (((byte >> 2) & 1u) | ((byte & 8u)   << 13)) * 0x3C00u;
    r.z = (((byte >> 4) & 1u) | ((byte & 32u)  << 11)) * 0x3C00u;
    r.w = (((byte >> 6) & 1u) | ((byte & 128u) << 9))  * 0x3C00u;
    return as_h8(r);
}

DEV float fast_tanh(float x) {
    float e = __expf(2.0f * x);
    return fmaf(-2.0f, __builtin_amdgcn_rcpf(e + 1.0f), 1.0f);
}

// ---- wide-read bit-pack: genes fp32 [256][T][64] -> gTb u64 [t][b] ----------
// Block = 256 consecutive rows R = b*T + t (64 KB dense). Thread reads 32 B
// (2 x float4 at row*256 + (tid&7)*32), emits 1 byte; 256 u64 rows in LDS;
// one barrier; thread tid stores row tid as 8-B (t-major scatter, 5.5 MB tot).
// Strata row counts (524288/131072/32768) are multiples of 256: no straddle.
__global__ __launch_bounds__(256, 8) void k_pack_all(
        const float* __restrict__ g3s, const float* __restrict__ g2s,
        const float* __restrict__ g1s,
        u64* __restrict__ d3, u64* __restrict__ d2, u64* __restrict__ d1) {
    __shared__ u64 rows[256];
    constexpr int R3 = B_ * T3_;          // 524288
    constexpr int R2 = B_ * T2_;          // 131072
    int B0 = blockIdx.x * 256;
    const float* src; u64* dst; int shift;
    if (B0 < R3)            { src = g3s; dst = d3; shift = 11; }
    else if (B0 < R3 + R2)  { B0 -= R3; src = g2s; dst = d2; shift = 9; }
    else                    { B0 -= R3 + R2; src = g1s; dst = d1; shift = 7; }
    const int tid = threadIdx.x;
    const int rloc = tid >> 3, byi = tid & 7;   // 8 threads per row
    u8* bts = (u8*)rows;
#pragma unroll
    for (int p = 0; p < 8; ++p) {
        const int row = p * 32 + rloc;
        const float4* rp = (const float4*)(src + (size_t)(B0 + row) * G_ + byi * 8);
        float4 f0 = rp[0], f1 = rp[1];
        uint bb = (f0.x != 0.f ?   1u : 0u) | (f0.y != 0.f ?   2u : 0u) |
                  (f0.z != 0.f ?   4u : 0u) | (f0.w != 0.f ?   8u : 0u) |
                  (f1.x != 0.f ?  16u : 0u) | (f1.y != 0.f ?  32u : 0u) |
                  (f1.z != 0.f ?  64u : 0u) | (f1.w != 0.f ? 128u : 0u);
        bts[row * 8 + byi] = (u8)bb;          // byte byi of row's u64 (LE)
    }
    __syncthreads();
    const int R = B0 + tid;
    const int b = R >> shift, t = R - (b << shift);
    dst[(size_t)t * B_ + b] = rows[tid];
}

// ---- MFMA GEMM + BN + tanh for strata 3/2/1; fp16 term-major output ---------
template <int T, int NCHILD>
__global__ __launch_bounds__(256, 4) void k_gemm(const __half* __restrict__ hsrc,
                                                 const u64* __restrict__ gTb,
                                                 const float* __restrict__ W,
                                                 const float* __restrict__ g,
                                                 const float* __restrict__ be,
                                                 __half* __restrict__ hout) {
    constexpr int K_IN = NCHILD * 20 + 64;
    constexpr int NK = NCHILD + 2;
    constexpr int STRB = NCHILD ? 200 : 72;          // WT row stride in halfs
    constexpr int LDSH = (32 * STRB > B_ * D_) ? 32 * STRB : B_ * D_;
    __shared__ __align__(16) __half WT[LDSH];        // weights, then h-tile
    __shared__ float gv[D_], bev[D_];
    __shared__ float sred[4][16], qred[4][16];

    const int t = blockIdx.x, tid = threadIdx.x;

    if (NCHILD) {   // k-pad rows must be 0; gemm3 (K=64 exact) skips this
        uint* WTu = (uint*)WT;
        for (int j = tid; j < 32 * STRB / 2; j += 256) WTu[j] = 0;
        __syncthreads();
    }
    if (tid < D_) { gv[tid] = g[t * D_ + tid]; bev[tid] = be[t * D_ + tid]; }
    const float* Wt = W + (size_t)t * (K_IN * D_);
    for (int j = tid; j < K_IN * D_; j += 256) {
        int k_orig = j / D_, o = j - k_orig * D_;
        int k_lds;
        if (NCHILD && k_orig < NCHILD * D_) {
            int c = k_orig / D_;
            k_lds = c * 32 + (k_orig - c * D_);
        } else {
            k_lds = NCHILD * 32 + (k_orig - NCHILD * D_);
        }
        WT[o * STRB + k_lds] = __float2half(Wt[j]);
    }
    __syncthreads();

    const int w = tid >> 6, lane = tid & 63;
    const int quad = lane >> 4, l15 = lane & 15;
    const int nt = w >> 1, mhalf = w & 1;
    const int ocol = nt * 16 + l15;                   // 0..31, valid < 20
    const int brow_base = mhalf * 128;                // 8 m-tiles of 16 rows
    const int shq = quad * 8;

    half8_t Bf[NK];
#pragma unroll
    for (int ks = 0; ks < NK; ++ks)
        Bf[ks] = as_h8(*(const uint4*)(WT + ocol * STRB + ks * 32 + quad * 8));

    f32x4 acc[8];
#pragma unroll
    for (int mt = 0; mt < 8; ++mt) acc[mt] = (f32x4){0.f, 0.f, 0.f, 0.f};

#pragma unroll
    for (int mt = 0; mt < 8; ++mt) {
        const int bA = brow_base + mt * 16 + l15;     // A-operand row = lane&15
        const uint2 gu = ((const uint2*)gTb)[(size_t)t * B_ + bA];   // 64 gene bits
#pragma unroll
        for (int c = 0; c < NCHILD; ++c) {
            // h row is 20 halfs; quad*8 may run past 20 into the next row:
            // finite garbage x zero-padded WT => exact 0 contribution.
            const __half* ap = hsrc + ((size_t)(NCHILD * t + c) * B_ + bA) * D_ + quad * 8;
            uint2 u0 = *(const uint2*)(ap);
            uint2 u1 = *(const uint2*)(ap + 4);
            acc[mt] = __builtin_amdgcn_mfma_f32_16x16x32_f16(
                as_h8(make_uint4(u0.x, u0.y, u1.x, u1.y)), Bf[c], acc[mt], 0, 0, 0);
        }
        acc[mt] = __builtin_amdgcn_mfma_f32_16x16x32_f16(
            bits8_to_h8((gu.x >> shq) & 0xFFu), Bf[NCHILD], acc[mt], 0, 0, 0);
        acc[mt] = __builtin_amdgcn_mfma_f32_16x16x32_f16(
            bits8_to_h8((gu.y >> shq) & 0xFFu), Bf[NCHILD + 1], acc[mt], 0, 0, 0);
    }

    // BN stats over batch: C/D layout row = quad*4+r, col = l15.
    float s = 0.f, q = 0.f;
#pragma unroll
    for (int mt = 0; mt < 8; ++mt)
#pragma unroll
        for (int r = 0; r < 4; ++r) {
            float z = acc[mt][r];
            s += z; q += z * z;
        }
    s += __shfl_xor(s, 16, 64); q += __shfl_xor(q, 16, 64);
    s += __shfl_xor(s, 32, 64); q += __shfl_xor(q, 32, 64);
    if (lane < 16) { sred[w][lane] = s; qred[w][lane] = q; }
    __syncthreads();        // after this no wave reads WT again (Bf in regs)
    const float S = sred[2 * nt][l15] + sred[2 * nt + 1][l15];
    const float Q = qred[2 * nt][l15] + qred[2 * nt + 1][l15];
    const float mu  = S * (1.0f / B_);
    const float var = fmaxf(Q * (1.0f / B_) - mu * mu, 0.0f);
    const float rstd = rsqrtf(var + EPS_);
    const int oc = ocol < D_ ? ocol : D_ - 1;
    const float A = rstd * gv[oc];
    const float C = bev[oc] - mu * A;

    // epilogue: LDS transpose (reuse WT) then dense uint4 stores (10 KB/term)
    if (ocol < D_) {
#pragma unroll
        for (int mt = 0; mt < 8; ++mt)
#pragma unroll
            for (int r = 0; r < 4; ++r) {
                float h = fast_tanh(fmaf(A, acc[mt][r], C));
                int b = brow_base + mt * 16 + quad * 4 + r;
                WT[b * D_ + ocol] = __float2half(h);
            }
    }
    __syncthreads();
    const uint4* src4 = (const uint4*)WT;
    uint4* dst4 = (uint4*)(hout + (size_t)t * (B_ * D_));
    for (int j = tid; j < (B_ * D_) / 8; j += 256) dst4[j] = src4[j];
}

// ---- root GEMV, K-split x4 (h1 fp16 term-major [t][b][20]) ------------------
__global__ __launch_bounds__(256, 4) void k_stage0a(const __half* __restrict__ h1,
                                                    const float* __restrict__ genes0,
                                                    const float* __restrict__ W0,
                                                    float* __restrict__ z0p) {
    const int b = blockIdx.x >> 2, s = blockIdx.x & 3, tid = threadIdx.x;
    const int kbase = 640 * s;
    float acc[D_] = {};
#pragma unroll
    for (int j = 0; j < 3; ++j) {
        int kl = tid + 256 * j;
        if (kl < 640) {
            int k = kbase + kl;
            int tt = k / D_, o = k - tt * D_;
            float xk = __half2float(h1[((size_t)tt * B_ + b) * D_ + o]);
            const float4* w = (const float4*)(W0 + (size_t)k * D_);
#pragma unroll
            for (int v = 0; v < D_ / 4; ++v) {
                float4 f = w[v];
                acc[4 * v + 0] = fmaf(xk, f.x, acc[4 * v + 0]);
                acc[4 * v + 1] = fmaf(xk, f.y, acc[4 * v + 1]);
                acc[4 * v + 2] = fmaf(xk, f.z, acc[4 * v + 2]);
                acc[4 * v + 3] = fmaf(xk, f.w, acc[4 * v + 3]);
            }
        }
    }
    if (s == 3 && tid < G_) {
        float xk = genes0[(size_t)b * G_ + tid];
        const float4* w = (const float4*)(W0 + (size_t)(T1_ * D_ + tid) * D_);
#pragma unroll
        for (int v = 0; v < D_ / 4; ++v) {
            float4 f = w[v];
            acc[4 * v + 0] = fmaf(xk, f.x, acc[4 * v + 0]);
            acc[4 * v + 1] = fmaf(xk, f.y, acc[4 * v + 1]);
            acc[4 * v + 2] = fmaf(xk, f.z, acc[4 * v + 2]);
            acc[4 * v + 3] = fmaf(xk, f.w, acc[4 * v + 3]);
        }
    }
    __shared__ float sred[4][D_];
    const int lane = tid & 63, wave = tid >> 6;
#pragma unroll
    for (int off = 32; off; off >>= 1)
#pragma unroll
        for (int o = 0; o < D_; ++o) acc[o] += __shfl_xor(acc[o], off, 64);
    if (lane == 0)
#pragma unroll
        for (int o = 0; o < D_; ++o) sred[wave][o] = acc[o];
    __syncthreads();
    if (tid < D_)
        z0p[((size_t)b * 4 + s) * D_ + tid] =
            sred[0][tid] + sred[1][tid] + sred[2][tid] + sred[3][tid];
}

// ---- root BN + tanh + head --------------------------------------------------
__global__ __launch_bounds__(256) void k_stage0b(const float* __restrict__ z0p,
                                                 const float* __restrict__ g0,
                                                 const float* __restrict__ be0,
                                                 const float* __restrict__ hw0,
                                                 const float* __restrict__ hb0,
                                                 float* __restrict__ out) {
    const int tid = threadIdx.x;   // == batch row
    float acc[D_] = {};
#pragma unroll
    for (int s = 0; s < 4; ++s) {
        const float4* zp = (const float4*)(z0p + ((size_t)tid * 4 + s) * D_);
#pragma unroll
        for (int v = 0; v < D_ / 4; ++v) {
            float4 f = zp[v];
            acc[4 * v + 0] += f.x; acc[4 * v + 1] += f.y;
            acc[4 * v + 2] += f.z; acc[4 * v + 3] += f.w;
        }
    }
    __shared__ float sred[4][D_], qred[4][D_], Avec[D_], Cvec[D_], hwv[D_ + 1];
    const int lane = tid & 63, wave = tid >> 6;
    float s[D_], q[D_];
#pragma unroll
    for (int o = 0; o < D_; ++o) { s[o] = acc[o]; q[o] = acc[o] * acc[o]; }
#pragma unroll
    for (int off = 32; off; off >>= 1) {
#pragma unroll
        for (int o = 0; o < D_; ++o) {
            s[o] += __shfl_xor(s[o], off, 64);
            q[o] += __shfl_xor(q[o], off, 64);
        }
    }
    if (lane == 0) {
#pragma unroll
        for (int o = 0; o < D_; ++o) { sred[wave][o] = s[o]; qred[wave][o] = q[o]; }
    }
    __syncthreads();
    if (tid < D_) {
        float S = sred[0][tid] + sred[1][tid] + sred[2][tid] + sred[3][tid];
        float Q = qred[0][tid] + qred[1][tid] + qred[2][tid] + qred[3][tid];
        float mu  = S * (1.0f / B_);
        float var = fmaxf(Q * (1.0f / B_) - mu * mu, 0.0f);
        float rstd = rsqrtf(var + EPS_);
        float A = rstd * g0[tid];
        Avec[tid] = A;
        Cvec[tid] = be0[tid] - mu * A;
        hwv[tid] = hw0[tid];
    }
    if (tid == 0) hwv[D_] = hb0[0];
    __syncthreads();
    float pred = hwv[D_];
#pragma unroll
    for (int o = 0; o < D_; ++o) {
        float h = fast_tanh(fmaf(acc[o], Avec[o], Cvec[o]));
        pred = fmaf(h, hwv[o], pred);
    }
    out[tid] = pred;
}

extern "C" void kernel_launch(void* const* d_in, const int* in_sizes, int n_in,
                              void* d_out, int out_size, void* d_ws, size_t ws_size,
                              hipStream_t stream) {
    const float* genes3 = (const float*)d_in[0];
    const float* genes2 = (const float*)d_in[1];
    const float* genes1 = (const float*)d_in[2];
    const float* genes0 = (const float*)d_in[3];
    const float* W3  = (const float*)d_in[4];
    const float* g3  = (const float*)d_in[6];
    const float* be3 = (const float*)d_in[7];
    const float* W2  = (const float*)d_in[8];
    const float* g2  = (const float*)d_in[10];
    const float* be2 = (const float*)d_in[11];
    const float* W1  = (const float*)d_in[12];
    const float* g1  = (const float*)d_in[14];
    const float* be1 = (const float*)d_in[15];
    const float* W0  = (const float*)d_in[16];
    const float* g0  = (const float*)d_in[18];
    const float* be0 = (const float*)d_in[19];
    const float* hw0 = (const float*)d_in[20];
    const float* hb0 = (const float*)d_in[21];

    char* wsb = (char*)d_ws;
    u64* gTb3 = (u64*)(wsb + OFF_GTB3);
    u64* gTb2 = (u64*)(wsb + OFF_GTB2);
    u64* gTb1 = (u64*)(wsb + OFF_GTB1);
    __half* h3  = (__half*)(wsb + OFF_H3B);
    __half* h2  = (__half*)(wsb + OFF_H2B);
    __half* h1  = (__half*)(wsb + OFF_H1B);
    float*  z0p = (float*)(wsb + OFF_Z0B);

    // total rows = (2048+512+128)*256 = 688128; 256 rows per block
    k_pack_all<<<688128 / 256, 256, 0, stream>>>(genes3, genes2, genes1,
                                                 gTb3, gTb2, gTb1);
    k_gemm<T3_, 0><<<T3_, 256, 0, stream>>>(nullptr, gTb3, W3, g3, be3, h3);
    k_gemm<T2_, 4><<<T2_, 256, 0, stream>>>(h3, gTb2, W2, g2, be2, h2);
    k_gemm<T1_, 4><<<T1_, 256, 0, stream>>>(h2, gTb1, W1, g1, be1, h1);
    k_stage0a<<<B_ * 4, 256, 0, stream>>>(h1, genes0, W0, z0p);
    k_stage0b<<<1, 256, 0, stream>>>(z0p, g0, be0, hw0, hb0, (float*)d_out);
}

// Round 14
// 321.312 us; speedup vs baseline: 1.0263x; 1.0263x over previous
//
#include <hip/hip_runtime.h>
#include <hip/hip_fp16.h>

// DCell forward, MI355X (gfx950). All inputs/outputs fp32.
// FINAL (revert to R12 best-measured config, 322.5 us):
// - ballot bit-pack: lane l reads gene l (dense 256B/wave-instr), __ballot
//   IS the u64 gene bitmask in MFMA A-frag order; HBM-bound (~30us, floor).
// - per-term MFMA 16x16x32 f16 GEMMs; only W staged in LDS; gene A-frags
//   expanded from bits via exact trick ((b0|b1<<16)*0x3C00, no carries).
// - BatchNorm block-local (256 rows/term); linear bias cancels in BN.
// - LDS-transposed dense uint4 epilogues; h3/h2/h1 fp16 term-major.
// Structural ceiling: timed window = 512MB ws-poison fill (78us @86% HBM
// peak) + ~195MB input restores + ~100us kernels vs ~70us traffic floor.
// ws: [gTb3 u64 | gTb2 | gTb1 | h3 fp16 | h2 fp16 | h1 fp16 | z0p] ~33 MB.

#define DEV static __device__ __forceinline__

constexpr int B_  = 256, G_ = 64, D_ = 20;
constexpr int T3_ = 2048, T2_ = 512, T1_ = 128;
constexpr float EPS_ = 1e-5f;

typedef unsigned char u8;
typedef unsigned long long u64;

constexpr size_t OFF_GTB3 = 0;
constexpr size_t SZ_GTB3 = (size_t)T3_ * B_ * 8;
constexpr size_t OFF_GTB2 = OFF_GTB3 + SZ_GTB3;
constexpr size_t SZ_GTB2 = (size_t)T2_ * B_ * 8;
constexpr size_t OFF_GTB1 = OFF_GTB2 + SZ_GTB2;
constexpr size_t SZ_GTB1 = (size_t)T1_ * B_ * 8;
constexpr size_t OFF_H3B = OFF_GTB1 + SZ_GTB1;
constexpr size_t SZ_H3 = (size_t)T3_ * B_ * D_ * 2;
constexpr size_t OFF_H2B = OFF_H3B + SZ_H3;
constexpr size_t SZ_H2 = (size_t)T2_ * B_ * D_ * 2;
constexpr size_t OFF_H1B = OFF_H2B + SZ_H2;
constexpr size_t SZ_H1 = (size_t)T1_ * B_ * D_ * 2;
constexpr size_t OFF_Z0B = OFF_H1B + SZ_H1;

typedef _Float16 half8_t __attribute__((ext_vector_type(8)));
typedef float f32x4 __attribute__((ext_vector_type(4)));

DEV half8_t as_h8(uint4 u) {
    union { uint4 u4; half8_t h; } c; c.u4 = u; return c.h;
}

// 8 gene BITS -> half8 {0.0h,1.0h}. Exact (no carries: operands are 0/1).
DEV half8_t bits8_to_h8(uint byte) {
    uint4 r;
    r.x = ((byte & 1u)        | ((byte & 2u)   << 15)) * 0x3C00u;
    r.y = (((byte >> 2) & 1u) | ((byte & 8u)   << 13)) * 0x3C00u;
    r.z = (((byte >> 4) & 1u) | ((byte & 32u)  << 11)) * 0x3C00u;
    r.w = (((byte >> 6) & 1u) | ((byte & 128u) << 9))  * 0x3C00u;
    return as_h8(r);
}

DEV float fast_tanh(float x) {
    float e = __expf(2.0f * x);
    return fmaf(-2.0f, __builtin_amdgcn_rcpf(e + 1.0f), 1.0f);
}

// ---- ballot bit-pack: genes fp32 [256][T][64] -> gTb u64 [t][b] -------------
__global__ __launch_bounds__(256, 8) void k_pack_all(
        const float* __restrict__ g3s, const float* __restrict__ g2s,
        const float* __restrict__ g1s,
        u64* __restrict__ d3, u64* __restrict__ d2, u64* __restrict__ d1) {
    constexpr int R3 = B_ * T3_;          // 524288
    constexpr int R2 = B_ * T2_;          // 131072
    const int lane = threadIdx.x & 63;
    int R0 = (blockIdx.x * 4 + (threadIdx.x >> 6)) * 8;
    const float* src; u64* dst; int shift;
    if (R0 < R3)            { src = g3s; dst = d3; shift = 11; }
    else if (R0 < R3 + R2)  { R0 -= R3; src = g2s; dst = d2; shift = 9; }
    else                    { R0 -= R3 + R2; src = g1s; dst = d1; shift = 7; }

    const float* p = src + (size_t)R0 * G_ + lane;
    float x[8];
#pragma unroll
    for (int r = 0; r < 8; ++r) x[r] = p[r * G_];
    u64 m[8];
#pragma unroll
    for (int r = 0; r < 8; ++r) m[r] = __ballot(x[r] != 0.0f);

    if (lane < 8) {
        u64 v = m[0];
        v = lane == 1 ? m[1] : v;
        v = lane == 2 ? m[2] : v;
        v = lane == 3 ? m[3] : v;
        v = lane == 4 ? m[4] : v;
        v = lane == 5 ? m[5] : v;
        v = lane == 6 ? m[6] : v;
        v = lane == 7 ? m[7] : v;
        const int R = R0 + lane;
        const int b = R >> shift, t = R - (b << shift);
        dst[(size_t)t * B_ + b] = v;
    }
}

// ---- MFMA GEMM + BN + tanh for strata 3/2/1; fp16 term-major output ---------
template <int T, int NCHILD>
__global__ __launch_bounds__(256, 4) void k_gemm(const __half* __restrict__ hsrc,
                                                 const u64* __restrict__ gTb,
                                                 const float* __restrict__ W,
                                                 const float* __restrict__ g,
                                                 const float* __restrict__ be,
                                                 __half* __restrict__ hout) {
    constexpr int K_IN = NCHILD * 20 + 64;
    constexpr int NK = NCHILD + 2;
    constexpr int STRB = NCHILD ? 200 : 72;          // WT row stride in halfs
    constexpr int LDSH = (32 * STRB > B_ * D_) ? 32 * STRB : B_ * D_;
    __shared__ __align__(16) __half WT[LDSH];        // weights, then h-tile
    __shared__ float gv[D_], bev[D_];
    __shared__ float sred[4][16], qred[4][16];

    const int t = blockIdx.x, tid = threadIdx.x;

    if (NCHILD) {   // k-pad rows must be 0; gemm3 (K=64 exact) skips this
        uint* WTu = (uint*)WT;
        for (int j = tid; j < 32 * STRB / 2; j += 256) WTu[j] = 0;
        __syncthreads();
    }
    if (tid < D_) { gv[tid] = g[t * D_ + tid]; bev[tid] = be[t * D_ + tid]; }
    const float* Wt = W + (size_t)t * (K_IN * D_);
    for (int j = tid; j < K_IN * D_; j += 256) {
        int k_orig = j / D_, o = j - k_orig * D_;
        int k_lds;
        if (NCHILD && k_orig < NCHILD * D_) {
            int c = k_orig / D_;
            k_lds = c * 32 + (k_orig - c * D_);
        } else {
            k_lds = NCHILD * 32 + (k_orig - NCHILD * D_);
        }
        WT[o * STRB + k_lds] = __float2half(Wt[j]);
    }
    __syncthreads();

    const int w = tid >> 6, lane = tid & 63;
    const int quad = lane >> 4, l15 = lane & 15;
    const int nt = w >> 1, mhalf = w & 1;
    const int ocol = nt * 16 + l15;                   // 0..31, valid < 20
    const int brow_base = mhalf * 128;                // 8 m-tiles of 16 rows
    const int shq = quad * 8;

    half8_t Bf[NK];
#pragma unroll
    for (int ks = 0; ks < NK; ++ks)
        Bf[ks] = as_h8(*(const uint4*)(WT + ocol * STRB + ks * 32 + quad * 8));

    f32x4 acc[8];
#pragma unroll
    for (int mt = 0; mt < 8; ++mt) acc[mt] = (f32x4){0.f, 0.f, 0.f, 0.f};

#pragma unroll
    for (int mt = 0; mt < 8; ++mt) {
        const int bA = brow_base + mt * 16 + l15;     // A-operand row = lane&15
        const uint2 gu = ((const uint2*)gTb)[(size_t)t * B_ + bA];   // 64 gene bits
#pragma unroll
        for (int c = 0; c < NCHILD; ++c) {
            // h row is 20 halfs; quad*8 may run past 20 into the next row:
            // finite garbage x zero-padded WT => exact 0 contribution.
            const __half* ap = hsrc + ((size_t)(NCHILD * t + c) * B_ + bA) * D_ + quad * 8;
            uint2 u0 = *(const uint2*)(ap);
            uint2 u1 = *(const uint2*)(ap + 4);
            acc[mt] = __builtin_amdgcn_mfma_f32_16x16x32_f16(
                as_h8(make_uint4(u0.x, u0.y, u1.x, u1.y)), Bf[c], acc[mt], 0, 0, 0);
        }
        acc[mt] = __builtin_amdgcn_mfma_f32_16x16x32_f16(
            bits8_to_h8((gu.x >> shq) & 0xFFu), Bf[NCHILD], acc[mt], 0, 0, 0);
        acc[mt] = __builtin_amdgcn_mfma_f32_16x16x32_f16(
            bits8_to_h8((gu.y >> shq) & 0xFFu), Bf[NCHILD + 1], acc[mt], 0, 0, 0);
    }

    // BN stats over batch: C/D layout row = quad*4+r, col = l15.
    float s = 0.f, q = 0.f;
#pragma unroll
    for (int mt = 0; mt < 8; ++mt)
#pragma unroll
        for (int r = 0; r < 4; ++r) {
            float z = acc[mt][r];
            s += z; q += z * z;
        }
    s += __shfl_xor(s, 16, 64); q += __shfl_xor(q, 16, 64);
    s += __shfl_xor(s, 32, 64); q += __shfl_xor(q, 32, 64);
    if (lane < 16) { sred[w][lane] = s; qred[w][lane] = q; }
    __syncthreads();        // after this no wave reads WT again (Bf in regs)
    const float S = sred[2 * nt][l15] + sred[2 * nt + 1][l15];
    const float Q = qred[2 * nt][l15] + qred[2 * nt + 1][l15];
    const float mu  = S * (1.0f / B_);
    const float var = fmaxf(Q * (1.0f / B_) - mu * mu, 0.0f);
    const float rstd = rsqrtf(var + EPS_);
    const int oc = ocol < D_ ? ocol : D_ - 1;
    const float A = rstd * gv[oc];
    const float C = bev[oc] - mu * A;

    // epilogue: LDS transpose (reuse WT) then dense uint4 stores (10 KB/term)
    if (ocol < D_) {
#pragma unroll
        for (int mt = 0; mt < 8; ++mt)
#pragma unroll
            for (int r = 0; r < 4; ++r) {
                float h = fast_tanh(fmaf(A, acc[mt][r], C));
                int b = brow_base + mt * 16 + quad * 4 + r;
                WT[b * D_ + ocol] = __float2half(h);
            }
    }
    __syncthreads();
    const uint4* src4 = (const uint4*)WT;
    uint4* dst4 = (uint4*)(hout + (size_t)t * (B_ * D_));
    for (int j = tid; j < (B_ * D_) / 8; j += 256) dst4[j] = src4[j];
}

// ---- root GEMV, K-split x4 (h1 fp16 term-major [t][b][20]) ------------------
__global__ __launch_bounds__(256, 4) void k_stage0a(const __half* __restrict__ h1,
                                                    const float* __restrict__ genes0,
                                                    const float* __restrict__ W0,
                                                    float* __restrict__ z0p) {
    const int b = blockIdx.x >> 2, s = blockIdx.x & 3, tid = threadIdx.x;
    const int kbase = 640 * s;
    float acc[D_] = {};
#pragma unroll
    for (int j = 0; j < 3; ++j) {
        int kl = tid + 256 * j;
        if (kl < 640) {
            int k = kbase + kl;
            int tt = k / D_, o = k - tt * D_;
            float xk = __half2float(h1[((size_t)tt * B_ + b) * D_ + o]);
            const float4* w = (const float4*)(W0 + (size_t)k * D_);
#pragma unroll
            for (int v = 0; v < D_ / 4; ++v) {
                float4 f = w[v];
                acc[4 * v + 0] = fmaf(xk, f.x, acc[4 * v + 0]);
                acc[4 * v + 1] = fmaf(xk, f.y, acc[4 * v + 1]);
                acc[4 * v + 2] = fmaf(xk, f.z, acc[4 * v + 2]);
                acc[4 * v + 3] = fmaf(xk, f.w, acc[4 * v + 3]);
            }
        }
    }
    if (s == 3 && tid < G_) {
        float xk = genes0[(size_t)b * G_ + tid];
        const float4* w = (const float4*)(W0 + (size_t)(T1_ * D_ + tid) * D_);
#pragma unroll
        for (int v = 0; v < D_ / 4; ++v) {
            float4 f = w[v];
            acc[4 * v + 0] = fmaf(xk, f.x, acc[4 * v + 0]);
            acc[4 * v + 1] = fmaf(xk, f.y, acc[4 * v + 1]);
            acc[4 * v + 2] = fmaf(xk, f.z, acc[4 * v + 2]);
            acc[4 * v + 3] = fmaf(xk, f.w, acc[4 * v + 3]);
        }
    }
    __shared__ float sred[4][D_];
    const int lane = tid & 63, wave = tid >> 6;
#pragma unroll
    for (int off = 32; off; off >>= 1)
#pragma unroll
        for (int o = 0; o < D_; ++o) acc[o] += __shfl_xor(acc[o], off, 64);
    if (lane == 0)
#pragma unroll
        for (int o = 0; o < D_; ++o) sred[wave][o] = acc[o];
    __syncthreads();
    if (tid < D_)
        z0p[((size_t)b * 4 + s) * D_ + tid] =
            sred[0][tid] + sred[1][tid] + sred[2][tid] + sred[3][tid];
}

// ---- root BN + tanh + head --------------------------------------------------
__global__ __launch_bounds__(256) void k_stage0b(const float* __restrict__ z0p,
                                                 const float* __restrict__ g0,
                                                 const float* __restrict__ be0,
                                                 const float* __restrict__ hw0,
                                                 const float* __restrict__ hb0,
                                                 float* __restrict__ out) {
    const int tid = threadIdx.x;   // == batch row
    float acc[D_] = {};
#pragma unroll
    for (int s = 0; s < 4; ++s) {
        const float4* zp = (const float4*)(z0p + ((size_t)tid * 4 + s) * D_);
#pragma unroll
        for (int v = 0; v < D_ / 4; ++v) {
            float4 f = zp[v];
            acc[4 * v + 0] += f.x; acc[4 * v + 1] += f.y;
            acc[4 * v + 2] += f.z; acc[4 * v + 3] += f.w;
        }
    }
    __shared__ float sred[4][D_], qred[4][D_], Avec[D_], Cvec[D_], hwv[D_ + 1];
    const int lane = tid & 63, wave = tid >> 6;
    float s[D_], q[D_];
#pragma unroll
    for (int o = 0; o < D_; ++o) { s[o] = acc[o]; q[o] = acc[o] * acc[o]; }
#pragma unroll
    for (int off = 32; off; off >>= 1) {
#pragma unroll
        for (int o = 0; o < D_; ++o) {
            s[o] += __shfl_xor(s[o], off, 64);
            q[o] += __shfl_xor(q[o], off, 64);
        }
    }
    if (lane == 0) {
#pragma unroll
        for (int o = 0; o < D_; ++o) { sred[wave][o] = s[o]; qred[wave][o] = q[o]; }
    }
    __syncthreads();
    if (tid < D_) {
        float S = sred[0][tid] + sred[1][tid] + sred[2][tid] + sred[3][tid];
        float Q = qred[0][tid] + qred[1][tid] + qred[2][tid] + qred[3][tid];
        float mu  = S * (1.0f / B_);
        float var = fmaxf(Q * (1.0f / B_) - mu * mu, 0.0f);
        float rstd = rsqrtf(var + EPS_);
        float A = rstd * g0[tid];
        Avec[tid] = A;
        Cvec[tid] = be0[tid] - mu * A;
        hwv[tid] = hw0[tid];
    }
    if (tid == 0) hwv[D_] = hb0[0];
    __syncthreads();
    float pred = hwv[D_];
#pragma unroll
    for (int o = 0; o < D_; ++o) {
        float h = fast_tanh(fmaf(acc[o], Avec[o], Cvec[o]));
        pred = fmaf(h, hwv[o], pred);
    }
    out[tid] = pred;
}

extern "C" void kernel_launch(void* const* d_in, const int* in_sizes, int n_in,
                              void* d_out, int out_size, void* d_ws, size_t ws_size,
                              hipStream_t stream) {
    const float* genes3 = (const float*)d_in[0];
    const float* genes2 = (const float*)d_in[1];
    const float* genes1 = (const float*)d_in[2];
    const float* genes0 = (const float*)d_in[3];
    const float* W3  = (const float*)d_in[4];
    const float* g3  = (const float*)d_in[6];
    const float* be3 = (const float*)d_in[7];
    const float* W2  = (const float*)d_in[8];
    const float* g2  = (const float*)d_in[10];
    const float* be2 = (const float*)d_in[11];
    const float* W1  = (const float*)d_in[12];
    const float* g1  = (const float*)d_in[14];
    const float* be1 = (const float*)d_in[15];
    const float* W0  = (const float*)d_in[16];
    const float* g0  = (const float*)d_in[18];
    const float* be0 = (const float*)d_in[19];
    const float* hw0 = (const float*)d_in[20];
    const float* hb0 = (const float*)d_in[21];

    char* wsb = (char*)d_ws;
    u64* gTb3 = (u64*)(wsb + OFF_GTB3);
    u64* gTb2 = (u64*)(wsb + OFF_GTB2);
    u64* gTb1 = (u64*)(wsb + OFF_GTB1);
    __half* h3  = (__half*)(wsb + OFF_H3B);
    __half* h2  = (__half*)(wsb + OFF_H2B);
    __half* h1  = (__half*)(wsb + OFF_H1B);
    float*  z0p = (float*)(wsb + OFF_Z0B);

    // total rows = (2048+512+128)*256 = 688128; 32 rows per block
    k_pack_all<<<688128 / 32, 256, 0, stream>>>(genes3, genes2, genes1,
                                                gTb3, gTb2, gTb1);
    k_gemm<T3_, 0><<<T3_, 256, 0, stream>>>(nullptr, gTb3, W3, g3, be3, h3);
    k_gemm<T2_, 4><<<T2_, 256, 0, stream>>>(h3, gTb2, W2, g2, be2, h2);
    k_gemm<T1_, 4><<<T1_, 256, 0, stream>>>(h2, gTb1, W1, g1, be1, h1);
    k_stage0a<<<B_ * 4, 256, 0, stream>>>(h1, genes0, W0, z0p);
    k_stage0b<<<1, 256, 0, stream>>>(z0p, g0, be0, hw0, hb0, (float*)d_out);
}